// Round 1
// baseline (1042.449 us; speedup 1.0000x reference)
//
#include <hip/hip_runtime.h>
#include <hip/hip_cooperative_groups.h>

namespace cg = cooperative_groups;

#define BATCH   8
#define HH      512
#define WW      512
#define IMGPIX  (HH * WW)          // 262144 = 1<<18
#define NPIX    (BATCH * IMGPIX)   // 2097152
#define KFAC    60.0f
#define MAX_PAIRS 300
#define SKEL_BLOCKS 1024
#define SKEL_THREADS 256

// clamped binary-image read (outside -> 0), image layout [b][h][w] bytes
__device__ __forceinline__ int getpix(const unsigned char* __restrict__ img, int b, int h, int w) {
    if ((unsigned)h >= (unsigned)HH || (unsigned)w >= (unsigned)WW) return 0;
    return (int)img[(b << 18) + (h << 9) + w];
}

// ---------------- kernel 1: CE loss + binary mask ----------------
__global__ void prep_kernel(const float* __restrict__ pred, const int* __restrict__ target,
                            float* __restrict__ L, unsigned char* __restrict__ x) {
    int i = blockIdx.x * blockDim.x + threadIdx.x;
    if (i >= NPIX) return;
    int b = i >> 18;
    int hw = i & (IMGPIX - 1);
    float p0 = pred[((2 * b) << 18) + hw];
    float p1 = pred[((2 * b + 1) << 18) + hw];
    float m = fmaxf(p0, p1);
    float lse = m + logf(expf(p0 - m) + expf(p1 - m));
    int t = target[i];
    float pt = t ? p1 : p0;
    L[i] = lse - pt;                       // -log_softmax[target]
    x[i] = (p1 > p0) ? 1 : 0;              // argmax != 0  (tie -> argmax=0)
}

// ---------------- Zhang-Suen substep delete test ----------------
__device__ __forceinline__ int zs_delete(const unsigned char* __restrict__ img,
                                         int b, int h, int w, int first) {
    // caller guarantees center pixel == 1
    int P2 = getpix(img, b, h - 1, w);
    int P3 = getpix(img, b, h - 1, w + 1);
    int P4 = getpix(img, b, h,     w + 1);
    int P5 = getpix(img, b, h + 1, w + 1);
    int P6 = getpix(img, b, h + 1, w);
    int P7 = getpix(img, b, h + 1, w - 1);
    int P8 = getpix(img, b, h,     w - 1);
    int P9 = getpix(img, b, h - 1, w - 1);
    int Bn = P2 + P3 + P4 + P5 + P6 + P7 + P8 + P9;
    if (Bn < 2 || Bn > 6) return 0;
    int A = ((P2 == 0) & (P3 == 1)) + ((P3 == 0) & (P4 == 1))
          + ((P4 == 0) & (P5 == 1)) + ((P5 == 0) & (P6 == 1))
          + ((P6 == 0) & (P7 == 1)) + ((P7 == 0) & (P8 == 1))
          + ((P8 == 0) & (P9 == 1)) + ((P9 == 0) & (P2 == 1));
    if (A != 1) return 0;
    int c3, c4;
    if (first) { c3 = P2 & P4 & P6; c4 = P4 & P6 & P8; }
    else       { c3 = P2 & P4 & P8; c4 = P2 & P6 & P8; }
    return (c3 | c4) == 0;
}

// ---------------- kernel 2: cooperative skeletonize (iterate to fixpoint) ----------------
__global__ __launch_bounds__(SKEL_THREADS, 4)
void skel_kernel(unsigned char* __restrict__ x, unsigned char* __restrict__ y,
                 int* __restrict__ cnt) {
    cg::grid_group grid = cg::this_grid();
    int tid = blockIdx.x * blockDim.x + threadIdx.x;
    int nth = gridDim.x * blockDim.x;

    for (int i = tid; i < MAX_PAIRS; i += nth) cnt[i] = 0;
    grid.sync();

    for (int p = 0; p < MAX_PAIRS; ++p) {
        // substep 1: x -> y
        int changed = 0;
        for (int i = tid; i < NPIX; i += nth) {
            unsigned char v = x[i];
            int del = 0;
            if (v) {
                int b = i >> 18, h = (i >> 9) & (HH - 1), w = i & (WW - 1);
                del = zs_delete(x, b, h, w, 1);
            }
            y[i] = (unsigned char)(v & (del ^ 1));
            changed |= del;
        }
        if (__any(changed) && (threadIdx.x & 63) == 0) atomicAdd(&cnt[p], 1);
        grid.sync();

        // substep 2: y -> x
        changed = 0;
        for (int i = tid; i < NPIX; i += nth) {
            unsigned char v = y[i];
            int del = 0;
            if (v) {
                int b = i >> 18, h = (i >> 9) & (HH - 1), w = i & (WW - 1);
                del = zs_delete(y, b, h, w, 0);
            }
            x[i] = (unsigned char)(v & (del ^ 1));
            changed |= del;
        }
        if (__any(changed) && (threadIdx.x & 63) == 0) atomicAdd(&cnt[p], 1);
        grid.sync();

        int c = __hip_atomic_load(&cnt[p], __ATOMIC_RELAXED, __HIP_MEMORY_SCOPE_AGENT);
        if (c == 0) break;   // fixpoint: no deletions in either substep
    }
}

// ---------------- kernel 3: endpoint map C = skel && (ring sum == 1) ----------------
__global__ void endpoints_kernel(const unsigned char* __restrict__ x, unsigned char* __restrict__ C) {
    int i = blockIdx.x * blockDim.x + threadIdx.x;
    if (i >= NPIX) return;
    unsigned char v = x[i];
    int out = 0;
    if (v) {
        int b = i >> 18, h = (i >> 9) & (HH - 1), w = i & (WW - 1);
        int s = getpix(x, b, h - 1, w - 1) + getpix(x, b, h - 1, w) + getpix(x, b, h - 1, w + 1)
              + getpix(x, b, h,     w - 1)                          + getpix(x, b, h,     w + 1)
              + getpix(x, b, h + 1, w - 1) + getpix(x, b, h + 1, w) + getpix(x, b, h + 1, w + 1);
        out = (s == 1);
    }
    C[i] = (unsigned char)out;
}

// ---------------- kernel 4: horizontal 9-wide box sum (values <= 9, fits u8) ----------------
__global__ void rowsum_kernel(const unsigned char* __restrict__ C, unsigned char* __restrict__ S) {
    int i = blockIdx.x * blockDim.x + threadIdx.x;
    if (i >= NPIX) return;
    int b = i >> 18, h = (i >> 9) & (HH - 1), w = i & (WW - 1);
    int s = 0;
    #pragma unroll
    for (int d = -4; d <= 4; ++d) s += getpix(C, b, h, w + d);
    S[i] = (unsigned char)s;
}

// ---------------- kernel 5: vertical 9 box sum + weight + partial reduce ----------------
__global__ void final_kernel(const unsigned char* __restrict__ S, const float* __restrict__ L,
                             float* __restrict__ partial) {
    __shared__ float sm[256];
    int i = blockIdx.x * blockDim.x + threadIdx.x;
    float acc = 0.0f;
    if (i < NPIX) {
        int b = i >> 18, h = (i >> 9) & (HH - 1), w = i & (WW - 1);
        int n = 0;
        #pragma unroll
        for (int d = -4; d <= 4; ++d) n += getpix(S, b, h + d, w);
        float wm = n ? ((float)n * KFAC) : 1.0f;   // Wmap = N + (N==0), N = boxsum*K
        acc = wm * L[i];
    }
    sm[threadIdx.x] = acc;
    __syncthreads();
    for (int s = 128; s > 0; s >>= 1) {
        if (threadIdx.x < s) sm[threadIdx.x] += sm[threadIdx.x + s];
        __syncthreads();
    }
    if (threadIdx.x == 0) partial[blockIdx.x] = sm[0];
}

// ---------------- kernel 6: final reduce of block partials ----------------
__global__ void reduce_kernel(const float* __restrict__ partial, int n, float* __restrict__ out) {
    __shared__ float sm[256];
    float a = 0.0f;
    for (int i = threadIdx.x; i < n; i += 256) a += partial[i];
    sm[threadIdx.x] = a;
    __syncthreads();
    for (int s = 128; s > 0; s >>= 1) {
        if (threadIdx.x < s) sm[threadIdx.x] += sm[threadIdx.x + s];
        __syncthreads();
    }
    if (threadIdx.x == 0) out[0] = sm[0] * (1.0f / (float)NPIX);
}

extern "C" void kernel_launch(void* const* d_in, const int* in_sizes, int n_in,
                              void* d_out, int out_size, void* d_ws, size_t ws_size,
                              hipStream_t stream) {
    const float* pred  = (const float*)d_in[0];
    const int* target  = (const int*)d_in[1];
    float* out = (float*)d_out;
    char* ws = (char*)d_ws;

    // ws layout (bytes):
    //   [0,            8388608)  L   float[NPIX]
    //   [8388608,     10485760)  x   u8[NPIX]
    //   [10485760,    12582912)  y   u8[NPIX]   (reused as C after skeleton)
    //   [12582912,    14680064)  S   u8[NPIX]
    //   [14680064,    14681264)  cnt int[MAX_PAIRS]
    //   [14684160,    14716928)  partial float[8192]
    float* L          = (float*)(ws);
    unsigned char* x  = (unsigned char*)(ws + 8388608);
    unsigned char* y  = (unsigned char*)(ws + 10485760);
    unsigned char* S  = (unsigned char*)(ws + 12582912);
    int* cnt          = (int*)(ws + 14680064);
    float* partial    = (float*)(ws + 14684160);

    dim3 blk(256);
    dim3 grd(NPIX / 256);   // 8192 blocks

    prep_kernel<<<grd, blk, 0, stream>>>(pred, target, L, x);

    {
        void* args[] = { (void*)&x, (void*)&y, (void*)&cnt };
        hipLaunchCooperativeKernel((void*)skel_kernel, dim3(SKEL_BLOCKS), dim3(SKEL_THREADS),
                                   args, 0, stream);
    }

    unsigned char* C = y;   // y is dead after skeleton; reuse as endpoint map
    endpoints_kernel<<<grd, blk, 0, stream>>>(x, C);
    rowsum_kernel<<<grd, blk, 0, stream>>>(C, S);
    final_kernel<<<grd, blk, 0, stream>>>(S, L, partial);
    reduce_kernel<<<1, dim3(256), 0, stream>>>(partial, NPIX / 256, out);
}

// Round 2
// 81.783 us; speedup vs baseline: 12.7466x; 12.7466x over previous
//
#include <hip/hip_runtime.h>

#define BATCH   8
#define HH      512
#define WW      512
#define IMGPIX  (HH * WW)          // 262144 = 1<<18
#define NPIX    (BATCH * IMGPIX)   // 2097152
#define KFAC    60.0f
#define MAX_PAIRS 256
#define WPR     8                  // 64-bit words per 512-px row
#define LDSTR   9                  // padded row stride in words (bank-conflict pad)

// clamped binary-image byte read (outside -> 0), layout [b][h][w]
__device__ __forceinline__ int getpix(const unsigned char* __restrict__ img, int b, int h, int w) {
    if ((unsigned)h >= (unsigned)HH || (unsigned)w >= (unsigned)WW) return 0;
    return (int)img[(b << 18) + (h << 9) + w];
}

// ---------------- kernel 1: CE loss + packed binary mask ----------------
__global__ void prep_kernel(const float* __restrict__ pred, const int* __restrict__ target,
                            float* __restrict__ L, unsigned long long* __restrict__ xp) {
    int i = blockIdx.x * blockDim.x + threadIdx.x;
    if (i >= NPIX) return;
    int b = i >> 18;
    int hw = i & (IMGPIX - 1);
    float p0 = pred[((size_t)(2 * b) << 18) + hw];
    float p1 = pred[((size_t)(2 * b + 1) << 18) + hw];
    float m = fmaxf(p0, p1);
    float lse = m + logf(expf(p0 - m) + expf(p1 - m));
    int t = target[i];
    L[i] = lse - (t ? p1 : p0);            // -log_softmax[target]
    unsigned long long word = __ballot(p1 > p0);   // 64 consecutive pixels per wave
    if ((threadIdx.x & 63) == 0) xp[i >> 6] = word;
}

// ---------------- bit-sliced Zhang-Suen substep on one row (8 words) ----------------
#define FA(a,b,c,s,cy) { unsigned long long _x = (a)^(b); (s) = _x^(c); (cy) = ((a)&(b)) | ((c)&_x); }
#define HA(a,b,s,cy)   { (s) = (a)^(b); (cy) = (a)&(b); }

template<int FIRST>
__device__ __forceinline__ unsigned long long zs_row(
    const unsigned long long* U, const unsigned long long* M, const unsigned long long* D,
    unsigned long long* outrow)
{
    unsigned long long ch = 0;
    #pragma unroll
    for (int wc = 0; wc < WPR; ++wc) {
        unsigned long long Uc = U[wc], Mc = M[wc], Dc = D[wc];
        unsigned long long Up = wc     ? U[wc-1] : 0ULL;
        unsigned long long Mp = wc     ? M[wc-1] : 0ULL;
        unsigned long long Dp = wc     ? D[wc-1] : 0ULL;
        unsigned long long Un = wc < 7 ? U[wc+1] : 0ULL;
        unsigned long long Mn = wc < 7 ? M[wc+1] : 0ULL;
        unsigned long long Dn = wc < 7 ? D[wc+1] : 0ULL;
        // neighbor bitmaps (bit j = pixel w = wc*64+j)
        unsigned long long P2 = Uc;                        // N
        unsigned long long P6 = Dc;                        // S
        unsigned long long P3 = (Uc >> 1) | (Un << 63);    // NE
        unsigned long long P4 = (Mc >> 1) | (Mn << 63);    // E
        unsigned long long P5 = (Dc >> 1) | (Dn << 63);    // SE
        unsigned long long P9 = (Uc << 1) | (Up >> 63);    // NW
        unsigned long long P8 = (Mc << 1) | (Mp >> 63);    // W
        unsigned long long P7 = (Dc << 1) | (Dp >> 63);    // SW

        // Bn = popcount of 8 neighbors, bit-sliced (b3 b2 b1 b0)
        unsigned long long sa,ca, sb,cb, sc,cc, b0,cd, sd,ce, b1,cf, b2,b3;
        FA(P2,P3,P4, sa,ca);
        FA(P5,P6,P7, sb,cb);
        FA(P8,P9,sa, sc,cc);
        HA(sb,sc,    b0,cd);
        FA(ca,cb,cc, sd,ce);
        HA(sd,cd,    b1,cf);
        HA(ce,cf,    b2,b3);
        unsigned long long ge2 = b1 | b2 | b3;
        unsigned long long le6 = ~(b3 | (b0 & b1 & b2));

        // A == 1: exactly one 0->1 transition around the ring
        unsigned long long e, seen, two = 0;
        seen = (~P2) & P3;
        e = (~P3) & P4; two |= seen & e; seen |= e;
        e = (~P4) & P5; two |= seen & e; seen |= e;
        e = (~P5) & P6; two |= seen & e; seen |= e;
        e = (~P6) & P7; two |= seen & e; seen |= e;
        e = (~P7) & P8; two |= seen & e; seen |= e;
        e = (~P8) & P9; two |= seen & e; seen |= e;
        e = (~P9) & P2; two |= seen & e; seen |= e;
        unsigned long long A1 = seen & ~two;

        unsigned long long c34;
        if (FIRST) { unsigned long long t = P4 & P6; c34 = t & (P2 | P8); }
        else       { unsigned long long t = P2 & P8; c34 = t & (P4 | P6); }

        unsigned long long del = Mc & ge2 & le6 & A1 & ~c34;
        outrow[wc] = Mc ^ del;
        ch |= del;
    }
    return ch;
}

// ---------------- kernel 2: bit-parallel skeletonize, 1 block = 1 image ----------------
__global__ __launch_bounds__(512)
void skel_kernel(const unsigned long long* __restrict__ xp, unsigned char* __restrict__ xb)
{
    __shared__ unsigned long long img[HH * LDSTR];   // 36 KB, single buffer
    const int b = blockIdx.x;
    const int h = threadIdx.x;      // one row per thread

    const unsigned long long* src = xp + (size_t)b * (HH * WPR);
    #pragma unroll
    for (int wc = 0; wc < WPR; ++wc) img[h * LDSTR + wc] = src[h * WPR + wc];
    __syncthreads();

    unsigned long long U[WPR], M[WPR], D[WPR], nrow[WPR];

    for (int p = 0; p < MAX_PAIRS; ++p) {
        unsigned long long ch;
        // ---- substep 1 (first=true): load 3 rows -> regs, barrier, write in place
        #pragma unroll
        for (int wc = 0; wc < WPR; ++wc) {
            U[wc] = (h > 0)      ? img[(h-1) * LDSTR + wc] : 0ULL;
            M[wc] =                img[h     * LDSTR + wc];
            D[wc] = (h < HH - 1) ? img[(h+1) * LDSTR + wc] : 0ULL;
        }
        __syncthreads();
        ch = zs_row<1>(U, M, D, nrow);
        #pragma unroll
        for (int wc = 0; wc < WPR; ++wc) img[h * LDSTR + wc] = nrow[wc];
        __syncthreads();
        // ---- substep 2 (first=false)
        #pragma unroll
        for (int wc = 0; wc < WPR; ++wc) {
            U[wc] = (h > 0)      ? img[(h-1) * LDSTR + wc] : 0ULL;
            M[wc] =                img[h     * LDSTR + wc];
            D[wc] = (h < HH - 1) ? img[(h+1) * LDSTR + wc] : 0ULL;
        }
        __syncthreads();
        ch |= zs_row<0>(U, M, D, nrow);
        #pragma unroll
        for (int wc = 0; wc < WPR; ++wc) img[h * LDSTR + wc] = nrow[wc];
        if (!__syncthreads_or(ch != 0ULL)) break;   // fixpoint for this image
    }

    // ---- unpack bits -> bytes, fully coalesced (chunk = 8 px = 8 bytes)
    unsigned char* dst = xb + (size_t)b * IMGPIX;
    const int t = threadIdx.x;
    #pragma unroll 4
    for (int k = 0; k < 64; ++k) {
        int c = t + 512 * k;           // chunk index 0..32767
        int wi = c >> 3, g = c & 7;
        unsigned long long v = img[(wi >> 3) * LDSTR + (wi & 7)];
        unsigned long long bb = (v >> (8 * g)) & 0xFFULL;
        unsigned long long spread = (bb * 0x0101010101010101ULL) & 0x8040201008040201ULL;
        unsigned long long bytes = ((spread + 0x7f7f7f7f7f7f7f7fULL) >> 7) & 0x0101010101010101ULL;
        *(unsigned long long*)(dst + (size_t)c * 8) = bytes;
    }
}

// ---------------- kernel 3: endpoint map C = skel && (ring sum == 1) ----------------
__global__ void endpoints_kernel(const unsigned char* __restrict__ x, unsigned char* __restrict__ C) {
    int i = blockIdx.x * blockDim.x + threadIdx.x;
    if (i >= NPIX) return;
    unsigned char v = x[i];
    int out = 0;
    if (v) {
        int b = i >> 18, h = (i >> 9) & (HH - 1), w = i & (WW - 1);
        int s = getpix(x, b, h - 1, w - 1) + getpix(x, b, h - 1, w) + getpix(x, b, h - 1, w + 1)
              + getpix(x, b, h,     w - 1)                          + getpix(x, b, h,     w + 1)
              + getpix(x, b, h + 1, w - 1) + getpix(x, b, h + 1, w) + getpix(x, b, h + 1, w + 1);
        out = (s == 1);
    }
    C[i] = (unsigned char)out;
}

// ---------------- kernel 4: horizontal 9-wide box sum ----------------
__global__ void rowsum_kernel(const unsigned char* __restrict__ C, unsigned char* __restrict__ S) {
    int i = blockIdx.x * blockDim.x + threadIdx.x;
    if (i >= NPIX) return;
    int b = i >> 18, h = (i >> 9) & (HH - 1), w = i & (WW - 1);
    int s = 0;
    #pragma unroll
    for (int d = -4; d <= 4; ++d) s += getpix(C, b, h, w + d);
    S[i] = (unsigned char)s;
}

// ---------------- kernel 5: vertical 9 box sum + weight + partial reduce ----------------
__global__ void final_kernel(const unsigned char* __restrict__ S, const float* __restrict__ L,
                             float* __restrict__ partial) {
    __shared__ float sm[256];
    int i = blockIdx.x * blockDim.x + threadIdx.x;
    float acc = 0.0f;
    if (i < NPIX) {
        int b = i >> 18, h = (i >> 9) & (HH - 1), w = i & (WW - 1);
        int n = 0;
        #pragma unroll
        for (int d = -4; d <= 4; ++d) n += getpix(S, b, h + d, w);
        float wm = n ? ((float)n * KFAC) : 1.0f;   // Wmap = N + (N==0), N = boxsum*K
        acc = wm * L[i];
    }
    sm[threadIdx.x] = acc;
    __syncthreads();
    for (int s = 128; s > 0; s >>= 1) {
        if (threadIdx.x < s) sm[threadIdx.x] += sm[threadIdx.x + s];
        __syncthreads();
    }
    if (threadIdx.x == 0) partial[blockIdx.x] = sm[0];
}

// ---------------- kernel 6: final reduce ----------------
__global__ void reduce_kernel(const float* __restrict__ partial, int n, float* __restrict__ out) {
    __shared__ float sm[256];
    float a = 0.0f;
    for (int i = threadIdx.x; i < n; i += 256) a += partial[i];
    sm[threadIdx.x] = a;
    __syncthreads();
    for (int s = 128; s > 0; s >>= 1) {
        if (threadIdx.x < s) sm[threadIdx.x] += sm[threadIdx.x + s];
        __syncthreads();
    }
    if (threadIdx.x == 0) out[0] = sm[0] * (1.0f / (float)NPIX);
}

extern "C" void kernel_launch(void* const* d_in, const int* in_sizes, int n_in,
                              void* d_out, int out_size, void* d_ws, size_t ws_size,
                              hipStream_t stream) {
    const float* pred = (const float*)d_in[0];
    const int* target = (const int*)d_in[1];
    float* out = (float*)d_out;
    char* ws = (char*)d_ws;

    // ws layout (bytes):
    //   [0,         8388608)   L        float[NPIX]
    //   [8388608,   8650752)   xp       u64[NPIX/64]  (packed mask)
    //   [8650752,  10747904)   xb       u8[NPIX]      (skeleton bytes)
    //   [10747904, 12845056)   C        u8[NPIX]      (endpoints)
    //   [12845056, 14942208)   S        u8[NPIX]      (row box sums)
    //   [14942208, 14974976)   partial  float[8192]
    float* L               = (float*)(ws);
    unsigned long long* xp = (unsigned long long*)(ws + 8388608);
    unsigned char* xb      = (unsigned char*)(ws + 8650752);
    unsigned char* C       = (unsigned char*)(ws + 10747904);
    unsigned char* S       = (unsigned char*)(ws + 12845056);
    float* partial         = (float*)(ws + 14942208);

    dim3 blk(256);
    dim3 grd(NPIX / 256);   // 8192 blocks

    prep_kernel<<<grd, blk, 0, stream>>>(pred, target, L, xp);
    skel_kernel<<<dim3(BATCH), dim3(512), 0, stream>>>(xp, xb);
    endpoints_kernel<<<grd, blk, 0, stream>>>(xb, C);
    rowsum_kernel<<<grd, blk, 0, stream>>>(C, S);
    final_kernel<<<grd, blk, 0, stream>>>(S, L, partial);
    reduce_kernel<<<1, dim3(256), 0, stream>>>(partial, NPIX / 256, out);
}